// Round 2
// baseline (750.709 us; speedup 1.0000x reference)
//
#include <hip/hip_runtime.h>
#include <hip/hip_bf16.h>

#define E_CNT 160000
#define N_CNT 10000

#define INV_STEP   2.125f          /* 17/8 */
#define EMB_C      33.734292f      /* 1.14136 * e^2 * sqrt(16) */
#define INVS320    0.05590170f     /* 1/sqrt(320) */
#define INVS8      0.35355339f     /* 1/sqrt(8)   */
#define INV_SQRT3  0.57735027f
#define KSCALE     0.051031036f    /* 0.25 (w/sqrt16) * 1/sqrt(24) (fctp norm) */

/* ---- workspace layout (float offsets) ---- */
#define OFF_FLAG   0          /* 16 floats reserved (int flag at [0]) */
#define OFF_XF     16         /* 400000 */
#define OFF_EAF    400016     /* 640000 */
#define OFF_AMFF   1040016    /* 160000 */
#define OFF_WQ0F   1200016    /* 256 */
#define OFF_WQ1F   1200272    /* 64  */
#define OFF_WD0F   1200336    /* 256 */
#define OFF_WD1F   1200592    /* 64  */
#define OFF_WK1F   1200656    /* 256 */
#define OFF_WV1F   1200912    /* 256 */
#define OFF_WK2F   1201168    /* 9216 */
#define OFF_WV2F   1210384    /* 9216 */
#define OFF_P      1219600    /* 400000 */
#define OFF_EXPV   1619600    /* 160000 */
#define OFF_VBUF   1779600    /* 6400000 */
#define OFF_Z      8179600    /* 10000 */
#define OFF_ACC    8189600    /* 400000 */
/* total 8589600 floats = 34.4 MB */

static __device__ __forceinline__ float bf2f(__hip_bfloat16 b) { return __bfloat162float(b); }
static __device__ __forceinline__ float sanitize(float v) {
    return fminf(fmaxf(v, -1e30f), 1e30f);   /* strips NaN too (fmaxf(NaN,a)=a) */
}

// ---------------- dtype detect: fp32 data viewed as u16 has garbage even-halves ----------------
__global__ void detect_kernel(const unsigned short* __restrict__ xb, int* __restrict__ flag)
{
    if (threadIdx.x == 0 && blockIdx.x == 0) {
        int cnt = 0;
        for (int k = 0; k < 256; k += 2) {          /* even u16 = fp32 low mantissa halves */
            unsigned e = (unsigned)((xb[k] >> 7) & 0xFF);
            if (e >= 141) ++cnt;                     /* |v| >= 2^14: impossible for N(0,1) bf16 */
        }
        *flag = (cnt >= 8) ? 1 : 0;                  /* 1 = inputs are fp32 */
    }
}

// ---------------- ingest: normalize every float input to fp32 in ws ----------------
__global__ __launch_bounds__(256) void ingest_kernel(
    const void* __restrict__ x,   const void* __restrict__ ea,  const void* __restrict__ amf,
    const void* __restrict__ Wq0, const void* __restrict__ Wq1,
    const void* __restrict__ Wk1, const void* __restrict__ Wk2,
    const void* __restrict__ Wv1, const void* __restrict__ Wv2,
    const void* __restrict__ Wd0, const void* __restrict__ Wd1,
    float* __restrict__ ws)
{
    const int i = blockIdx.x * 256 + threadIdx.x;
    const int f32 = *(const int*)ws;
#define CV(p, idx) (f32 ? ((const float*)(p))[idx] : bf2f(((const __hip_bfloat16*)(p))[idx]))
    if (i < 400000) ws[OFF_XF + i]   = CV(x, i);
    if (i < 640000) ws[OFF_EAF + i]  = CV(ea, i);
    if (i < 160000) ws[OFF_AMFF + i] = CV(amf, i);
    if (i < 9216) { ws[OFF_WK2F + i] = CV(Wk2, i); ws[OFF_WV2F + i] = CV(Wv2, i); }
    if (i < 256) {
        ws[OFF_WQ0F + i] = CV(Wq0, i); ws[OFF_WD0F + i] = CV(Wd0, i);
        ws[OFF_WK1F + i] = CV(Wk1, i); ws[OFF_WV1F + i] = CV(Wv1, i);
    }
    if (i < 64) { ws[OFF_WQ1F + i] = CV(Wq1, i); ws[OFF_WD1F + i] = CV(Wd1, i); }
#undef CV
}

// ---------------- per-node: P = [q0@Wd0 (16), q1 contracted with Wd1 (8x3)] ----------------
__global__ __launch_bounds__(256) void node_kernel(float* __restrict__ ws)
{
    const int n = blockIdx.x * 256 + threadIdx.x;
    if (n >= N_CNT) return;
    const float* WQ0 = ws + OFF_WQ0F;
    const float* WQ1 = ws + OFF_WQ1F;
    const float* WD0 = ws + OFF_WD0F;
    const float* WD1 = ws + OFF_WD1F;
    float xs[40];
    const float4* xr = (const float4*)(ws + OFF_XF + n * 40);
#pragma unroll
    for (int k = 0; k < 10; ++k) {
        float4 f = xr[k];
        xs[4 * k + 0] = f.x; xs[4 * k + 1] = f.y; xs[4 * k + 2] = f.z; xs[4 * k + 3] = f.w;
    }
    float q0[16];
#pragma unroll
    for (int w = 0; w < 16; ++w) {
        float s = 0.f;
#pragma unroll
        for (int u = 0; u < 16; ++u) s = fmaf(xs[u], WQ0[u * 16 + w], s);
        q0[w] = s * 0.25f;   /* /sqrt(M0) */
    }
    float* pn = ws + OFF_P + n * 40;
#pragma unroll
    for (int v = 0; v < 16; ++v) {
        float s = 0.f;
#pragma unroll
        for (int w = 0; w < 16; ++w) s = fmaf(q0[w], WD0[w * 16 + v], s);
        pn[v] = sanitize(s * INVS320);
    }
    float q1[24];
#pragma unroll
    for (int w = 0; w < 8; ++w) {
        float s0 = 0.f, s1 = 0.f, s2 = 0.f;
#pragma unroll
        for (int u = 0; u < 8; ++u) {
            float wq = WQ1[u * 8 + w];
            s0 = fmaf(xs[16 + u * 3 + 0], wq, s0);
            s1 = fmaf(xs[16 + u * 3 + 1], wq, s1);
            s2 = fmaf(xs[16 + u * 3 + 2], wq, s2);
        }
        q1[w * 3 + 0] = s0 * INVS8;
        q1[w * 3 + 1] = s1 * INVS8;
        q1[w * 3 + 2] = s2 * INVS8;
    }
#pragma unroll
    for (int v = 0; v < 8; ++v) {
        float s0 = 0.f, s1 = 0.f, s2 = 0.f;
#pragma unroll
        for (int w = 0; w < 8; ++w) {
            float wd = WD1[w * 8 + v];
            s0 = fmaf(q1[w * 3 + 0], wd, s0);
            s1 = fmaf(q1[w * 3 + 1], wd, s1);
            s2 = fmaf(q1[w * 3 + 2], wd, s2);
        }
        const float sc = INVS320 * INV_SQRT3;  /* /sqrt(320) and the score1 /sqrt(3) */
        pn[16 + v * 3 + 0] = sanitize(s0 * sc);
        pn[16 + v * 3 + 1] = sanitize(s1 * sc);
        pn[16 + v * 3 + 2] = sanitize(s2 * sc);
    }
}

// ---------------- fused radial @ fctp pass ----------------
__device__ __forceinline__ void fctp_pass(
    const float* __restrict__ W2, const float* h_s, int tid, float sh0,
    const float (&xs0)[16], const float (&xs1)[24], const float (&dot11)[8],
    float (&o0)[16], float (&o1)[24], float (&t2a)[8])
{
#pragma unroll 1
    for (int c = 0; c < 16; ++c) {
        float hc = h_s[c * 256 + tid];
        float hs = hc * sh0;
        const float* row = W2 + c * 576;
        // seg1: w1 (16x16): o0[wo] += row[u*16+wo] * (hc*sh0*xs0[u])
#pragma unroll
        for (int u = 0; u < 16; ++u) {
            float au = hs * xs0[u];
            const float* r = row + u * 16;
#pragma unroll
            for (int wo = 0; wo < 16; ++wo) o0[wo] = fmaf(r[wo], au, o0[wo]);
        }
        // seg2: w2 (16x8): t2a[wo] += row[256+u*8+wo] * (hc*xs0[u])
#pragma unroll
        for (int u = 0; u < 16; ++u) {
            float bu = hc * xs0[u];
            const float* r = row + 256 + u * 8;
#pragma unroll
            for (int wo = 0; wo < 8; ++wo) t2a[wo] = fmaf(r[wo], bu, t2a[wo]);
        }
        // seg3: w3 (8x8): o1[wo*3+i] += row[384+u*8+wo] * (hc*sh0*xs1[u*3+i])
#pragma unroll
        for (int u = 0; u < 8; ++u) {
            float c0 = hs * xs1[u * 3 + 0];
            float c1 = hs * xs1[u * 3 + 1];
            float c2 = hs * xs1[u * 3 + 2];
            const float* r = row + 384 + u * 8;
#pragma unroll
            for (int wo = 0; wo < 8; ++wo) {
                float rv = r[wo];
                o1[wo * 3 + 0] = fmaf(rv, c0, o1[wo * 3 + 0]);
                o1[wo * 3 + 1] = fmaf(rv, c1, o1[wo * 3 + 1]);
                o1[wo * 3 + 2] = fmaf(rv, c2, o1[wo * 3 + 2]);
            }
        }
        // seg4: w4 (8x16): o0[wo] += row[448+u*16+wo] * (hc*dot11[u])
#pragma unroll
        for (int u = 0; u < 8; ++u) {
            float du = hc * dot11[u];
            const float* r = row + 448 + u * 16;
#pragma unroll
            for (int wo = 0; wo < 16; ++wo) o0[wo] = fmaf(r[wo], du, o0[wo]);
        }
    }
}

// ---------------- per-edge main kernel ----------------
__global__ __launch_bounds__(256) void edge_kernel(
    const int* __restrict__ ei, float* __restrict__ ws)
{
    __shared__ float hk_s[16 * 256];
    __shared__ float hv_s[16 * 256];
    const int tid = threadIdx.x;
    const int e = blockIdx.x * 256 + tid;
    if (e >= E_CNT) return;

    const float d = ws[OFF_AMFF + e];
    const float dsv = d * INV_STEP;
    float emb[16];
#pragma unroll
    for (int b = 0; b < 16; ++b) {
        float t1 = dsv - (float)b;          /* diff+1 */
        float t2 = (float)(b + 2) - dsv;    /* 1-diff */
        float v = 0.f;
        if (t1 > 0.f && t2 > 0.f) v = EMB_C * expf(-1.f / t1 - 1.f / t2);
        emb[b] = v;
    }
    float ct = 10.f * (1.f - d * 0.125f);
    float cutoff = (ct > 0.f) ? expf(-1.f / ct) : 0.f;

    const float* WK1 = ws + OFF_WK1F;
    const float* WV1 = ws + OFF_WV1F;

#pragma unroll 1
    for (int j = 0; j < 16; ++j) {
        float sk = 0.f, sv = 0.f;
#pragma unroll
        for (int b = 0; b < 16; ++b) {
            float eb = emb[b];
            sk = fmaf(eb, WK1[b * 16 + j], sk);
            sv = fmaf(eb, WV1[b * 16 + j], sv);
        }
        sk *= 0.25f; sv *= 0.25f;   /* /sqrt(NB) */
        hk_s[j * 256 + tid] = sk / (1.f + expf(-sk));   /* silu */
        hv_s[j * 256 + tid] = sv / (1.f + expf(-sv));
    }

    const int src = ei[e];
    const int dst = ei[E_CNT + e];

    float xs0[16], xs1[24];
    {
        const float4* xr = (const float4*)(ws + OFF_XF + src * 40);
#pragma unroll
        for (int k = 0; k < 4; ++k) {
            float4 f = xr[k];
            xs0[4 * k] = f.x; xs0[4 * k + 1] = f.y; xs0[4 * k + 2] = f.z; xs0[4 * k + 3] = f.w;
        }
#pragma unroll
        for (int k = 0; k < 6; ++k) {
            float4 f = xr[4 + k];
            xs1[4 * k] = f.x; xs1[4 * k + 1] = f.y; xs1[4 * k + 2] = f.z; xs1[4 * k + 3] = f.w;
        }
    }
    const float4 eav = ((const float4*)(ws + OFF_EAF))[e];
    const float sh0 = eav.x, sh1x = eav.y, sh1y = eav.z, sh1z = eav.w;

    float dot11[8];
#pragma unroll
    for (int u = 0; u < 8; ++u)
        dot11[u] = (xs1[u * 3] * sh1x + xs1[u * 3 + 1] * sh1y + xs1[u * 3 + 2] * sh1z) * INV_SQRT3;

    float o0[16], o1[24], t2a[8];

    // ================= K pass =================
#pragma unroll
    for (int i = 0; i < 16; ++i) o0[i] = 0.f;
#pragma unroll
    for (int i = 0; i < 24; ++i) o1[i] = 0.f;
#pragma unroll
    for (int i = 0; i < 8; ++i) t2a[i] = 0.f;
    fctp_pass(ws + OFF_WK2F, hk_s, tid, sh0, xs0, xs1, dot11, o0, o1, t2a);
#pragma unroll
    for (int wo = 0; wo < 8; ++wo) {
        o1[wo * 3 + 0] = fmaf(t2a[wo], sh1x, o1[wo * 3 + 0]);
        o1[wo * 3 + 1] = fmaf(t2a[wo], sh1y, o1[wo * 3 + 1]);
        o1[wo * 3 + 2] = fmaf(t2a[wo], sh1z, o1[wo * 3 + 2]);
    }
    const float* pd = ws + OFF_P + dst * 40;
    float sc = 0.f;
#pragma unroll
    for (int j = 0; j < 16; ++j) sc = fmaf(o0[j], pd[j], sc);
#pragma unroll
    for (int j = 0; j < 24; ++j) sc = fmaf(o1[j], pd[16 + j], sc);
    sc = fminf(fmaxf(sc * KSCALE, -60.f), 60.f);   /* NaN-proof + overflow-proof */
    float ev = cutoff * expf(sc);
    ev = fmaxf(ev, 0.f);                            /* strips NaN */
    ws[OFF_EXPV + e] = ev;
    atomicAdd(ws + OFF_Z + dst, ev);

    // ================= V pass =================
#pragma unroll
    for (int i = 0; i < 16; ++i) o0[i] = 0.f;
#pragma unroll
    for (int i = 0; i < 24; ++i) o1[i] = 0.f;
#pragma unroll
    for (int i = 0; i < 8; ++i) t2a[i] = 0.f;
    fctp_pass(ws + OFF_WV2F, hv_s, tid, sh0, xs0, xs1, dot11, o0, o1, t2a);
#pragma unroll
    for (int wo = 0; wo < 8; ++wo) {
        o1[wo * 3 + 0] = fmaf(t2a[wo], sh1x, o1[wo * 3 + 0]);
        o1[wo * 3 + 1] = fmaf(t2a[wo], sh1y, o1[wo * 3 + 1]);
        o1[wo * 3 + 2] = fmaf(t2a[wo], sh1z, o1[wo * 3 + 2]);
    }
    float* vr = ws + OFF_VBUF + (size_t)e * 40;
#pragma unroll
    for (int j = 0; j < 16; ++j) vr[j] = sanitize(o0[j] * KSCALE);
#pragma unroll
    for (int j = 0; j < 24; ++j) vr[16 + j] = sanitize(o1[j] * KSCALE);
}

// ---------------- scatter: out accumulation ----------------
__global__ __launch_bounds__(256) void scatter_kernel(
    const int* __restrict__ ei, float* __restrict__ ws)
{
    const int e = blockIdx.x * 256 + threadIdx.x;
    if (e >= E_CNT) return;
    const int dst = ei[E_CNT + e];
    float zz = ws[OFF_Z + dst];
    zz = (zz > 0.f) ? zz : 1.f;                     /* z==0 -> 1; also strips NaN/neg */
    const float we = sqrtf(fmaxf(ws[OFF_EXPV + e] / zz, 0.f));
    const float4* vr = (const float4*)(ws + OFF_VBUF + (size_t)e * 40);
    float* ar = ws + OFF_ACC + dst * 40;
#pragma unroll
    for (int q = 0; q < 10; ++q) {
        float4 v4 = vr[q];
        atomicAdd(ar + q * 4 + 0, we * v4.x);
        atomicAdd(ar + q * 4 + 1, we * v4.y);
        atomicAdd(ar + q * 4 + 2, we * v4.z);
        atomicAdd(ar + q * 4 + 3, we * v4.w);
    }
}

// ---------------- fp32 accum -> output (bf16 or fp32 per flag) ----------------
__global__ __launch_bounds__(256) void conv_kernel(
    const float* __restrict__ ws, void* __restrict__ out)
{
    const int i = blockIdx.x * 256 + threadIdx.x;
    if (i >= N_CNT * 40) return;
    const int f32 = *(const int*)ws;
    const float v = sanitize(ws[OFF_ACC + i]);
    if (f32) ((float*)out)[i] = v;
    else     ((__hip_bfloat16*)out)[i] = __float2bfloat16(v);
}

extern "C" void kernel_launch(void* const* d_in, const int* in_sizes, int n_in,
                              void* d_out, int out_size, void* d_ws, size_t ws_size,
                              hipStream_t stream)
{
    (void)in_sizes; (void)n_in; (void)out_size; (void)ws_size;
    const void* x   = d_in[0];
    const int*  ei  = (const int*)d_in[1];
    const void* ea  = d_in[2];
    /* d_in[3] node_attr, d_in[4] batch: unused by the reference math */
    const void* amf = d_in[5];
    const void* Wq0 = d_in[6];
    const void* Wq1 = d_in[7];
    const void* Wk1 = d_in[8];
    const void* Wk2 = d_in[9];
    const void* Wv1 = d_in[10];
    const void* Wv2 = d_in[11];
    const void* Wd0 = d_in[12];
    const void* Wd1 = d_in[13];

    float* ws = (float*)d_ws;

    detect_kernel<<<1, 64, 0, stream>>>((const unsigned short*)x, (int*)ws);
    hipMemsetAsync(ws + OFF_Z, 0, (10000 + 400000) * sizeof(float), stream); /* z + acc */
    ingest_kernel<<<2500, 256, 0, stream>>>(x, ea, amf, Wq0, Wq1, Wk1, Wk2, Wv1, Wv2, Wd0, Wd1, ws);
    node_kernel<<<(N_CNT + 255) / 256, 256, 0, stream>>>(ws);
    edge_kernel<<<E_CNT / 256, 256, 0, stream>>>(ei, ws);
    scatter_kernel<<<E_CNT / 256, 256, 0, stream>>>(ei, ws);
    conv_kernel<<<(N_CNT * 40 + 255) / 256, 256, 0, stream>>>(ws, d_out);
}

// Round 3
// 478.294 us; speedup vs baseline: 1.5696x; 1.5696x over previous
//
#include <hip/hip_runtime.h>
#include <hip/hip_bf16.h>

#define E_CNT 160000
#define N_CNT 10000

#define INV_STEP   2.125f          /* 17/8 */
#define EMB_C      33.734292f      /* 1.14136 * e^2 * sqrt(16) */
#define INVS320    0.05590170f     /* 1/sqrt(320) */
#define INVS8      0.35355339f     /* 1/sqrt(8)   */
#define INV_SQRT3  0.57735027f
#define KSCALE     0.051031036f    /* 0.25 (w/sqrt16) * 1/sqrt(24) (fctp norm) */

/* ---- workspace layout (float-sized offsets) ---- */
#define OFF_FLAG   0          /* 16 floats reserved (int flag at [0]) */
#define OFF_XF     16         /* 400000 */
#define OFF_EAF    400016     /* 640000 */
#define OFF_AMFF   1040016    /* 160000 */
#define OFF_WQ0F   1200016    /* 256 */
#define OFF_WQ1F   1200272    /* 64  */
#define OFF_WD0F   1200336    /* 256 */
#define OFF_WD1F   1200592    /* 64  */
#define OFF_WK1F   1200656    /* 256 */
#define OFF_WV1F   1200912    /* 256 */
#define OFF_WK2F   1201168    /* 9216 */
#define OFF_WV2F   1210384    /* 9216 */
#define OFF_P      1219600    /* 400000 */
#define OFF_EXPV   1619600    /* 160000 */
#define OFF_VBUF   1779600    /* 6400000 */
#define OFF_DEG    8179600    /* 10000 ints */
#define OFF_START  8189600    /* 10001 ints */
#define OFF_CURS   8199616    /* 10000 ints */
#define OFF_ELIST  8209616    /* 160000 ints */
/* total 8369616 floats = 33.5 MB */

static __device__ __forceinline__ float bf2f(__hip_bfloat16 b) { return __bfloat162float(b); }
static __device__ __forceinline__ float sanitize(float v) {
    return fminf(fmaxf(v, -1e30f), 1e30f);   /* strips NaN too (fmaxf(NaN,a)=a) */
}

// ---------------- dtype detect: fp32 data viewed as u16 has garbage even-halves ----------------
__global__ void detect_kernel(const unsigned short* __restrict__ xb, int* __restrict__ flag)
{
    if (threadIdx.x == 0 && blockIdx.x == 0) {
        int cnt = 0;
        for (int k = 0; k < 256; k += 2) {
            unsigned e = (unsigned)((xb[k] >> 7) & 0xFF);
            if (e >= 141) ++cnt;
        }
        *flag = (cnt >= 8) ? 1 : 0;   /* 1 = inputs are fp32 */
    }
}

// ---------------- ingest: normalize every float input to fp32 in ws ----------------
__global__ __launch_bounds__(256) void ingest_kernel(
    const void* __restrict__ x,   const void* __restrict__ ea,  const void* __restrict__ amf,
    const void* __restrict__ Wq0, const void* __restrict__ Wq1,
    const void* __restrict__ Wk1, const void* __restrict__ Wk2,
    const void* __restrict__ Wv1, const void* __restrict__ Wv2,
    const void* __restrict__ Wd0, const void* __restrict__ Wd1,
    float* __restrict__ ws)
{
    const int i = blockIdx.x * 256 + threadIdx.x;
    const int f32 = *(const int*)ws;
#define CV(p, idx) (f32 ? ((const float*)(p))[idx] : bf2f(((const __hip_bfloat16*)(p))[idx]))
    if (i < 400000) ws[OFF_XF + i]   = CV(x, i);
    if (i < 640000) ws[OFF_EAF + i]  = CV(ea, i);
    if (i < 160000) ws[OFF_AMFF + i] = CV(amf, i);
    if (i < 9216) { ws[OFF_WK2F + i] = CV(Wk2, i); ws[OFF_WV2F + i] = CV(Wv2, i); }
    if (i < 256) {
        ws[OFF_WQ0F + i] = CV(Wq0, i); ws[OFF_WD0F + i] = CV(Wd0, i);
        ws[OFF_WK1F + i] = CV(Wk1, i); ws[OFF_WV1F + i] = CV(Wv1, i);
    }
    if (i < 64) { ws[OFF_WQ1F + i] = CV(Wq1, i); ws[OFF_WD1F + i] = CV(Wd1, i); }
#undef CV
}

// ---------------- CSR build ----------------
__global__ __launch_bounds__(256) void count_kernel(const int* __restrict__ ei, float* __restrict__ ws)
{
    const int e = blockIdx.x * 256 + threadIdx.x;
    if (e >= E_CNT) return;
    atomicAdd((int*)(ws + OFF_DEG) + ei[E_CNT + e], 1);
}

__global__ __launch_bounds__(256) void scan_kernel(float* __restrict__ ws)
{
    __shared__ int ssum[256];
    const int t = threadIdx.x;
    int* deg   = (int*)(ws + OFF_DEG);
    int* start = (int*)(ws + OFF_START);
    int* curs  = (int*)(ws + OFF_CURS);
    const int base = t * 40;                       /* 256*40 = 10240 >= 10000 */
    int s = 0;
    for (int k = 0; k < 40; ++k) {
        int idx = base + k;
        if (idx < N_CNT) s += deg[idx];
    }
    ssum[t] = s;
    __syncthreads();
    for (int off = 1; off < 256; off <<= 1) {
        int v = (t >= off) ? ssum[t - off] : 0;
        __syncthreads();
        ssum[t] += v;
        __syncthreads();
    }
    int run = ssum[t] - s;                          /* exclusive prefix for this chunk */
    for (int k = 0; k < 40; ++k) {
        int idx = base + k;
        if (idx < N_CNT) {
            start[idx] = run;
            curs[idx]  = run;
            run += deg[idx];
        }
    }
    if (t == 255) start[N_CNT] = E_CNT;
}

__global__ __launch_bounds__(256) void fill_kernel(const int* __restrict__ ei, float* __restrict__ ws)
{
    const int e = blockIdx.x * 256 + threadIdx.x;
    if (e >= E_CNT) return;
    int pos = atomicAdd((int*)(ws + OFF_CURS) + ei[E_CNT + e], 1);
    ((int*)(ws + OFF_ELIST))[pos] = e;
}

// ---------------- per-node: P = [q0@Wd0 (16), q1 contracted with Wd1 (8x3)] ----------------
__global__ __launch_bounds__(256) void node_kernel(float* __restrict__ ws)
{
    const int n = blockIdx.x * 256 + threadIdx.x;
    if (n >= N_CNT) return;
    const float* WQ0 = ws + OFF_WQ0F;
    const float* WQ1 = ws + OFF_WQ1F;
    const float* WD0 = ws + OFF_WD0F;
    const float* WD1 = ws + OFF_WD1F;
    float xs[40];
    const float4* xr = (const float4*)(ws + OFF_XF + n * 40);
#pragma unroll
    for (int k = 0; k < 10; ++k) {
        float4 f = xr[k];
        xs[4 * k + 0] = f.x; xs[4 * k + 1] = f.y; xs[4 * k + 2] = f.z; xs[4 * k + 3] = f.w;
    }
    float q0[16];
#pragma unroll
    for (int w = 0; w < 16; ++w) {
        float s = 0.f;
#pragma unroll
        for (int u = 0; u < 16; ++u) s = fmaf(xs[u], WQ0[u * 16 + w], s);
        q0[w] = s * 0.25f;
    }
    float* pn = ws + OFF_P + n * 40;
#pragma unroll
    for (int v = 0; v < 16; ++v) {
        float s = 0.f;
#pragma unroll
        for (int w = 0; w < 16; ++w) s = fmaf(q0[w], WD0[w * 16 + v], s);
        pn[v] = sanitize(s * INVS320);
    }
    float q1[24];
#pragma unroll
    for (int w = 0; w < 8; ++w) {
        float s0 = 0.f, s1 = 0.f, s2 = 0.f;
#pragma unroll
        for (int u = 0; u < 8; ++u) {
            float wq = WQ1[u * 8 + w];
            s0 = fmaf(xs[16 + u * 3 + 0], wq, s0);
            s1 = fmaf(xs[16 + u * 3 + 1], wq, s1);
            s2 = fmaf(xs[16 + u * 3 + 2], wq, s2);
        }
        q1[w * 3 + 0] = s0 * INVS8;
        q1[w * 3 + 1] = s1 * INVS8;
        q1[w * 3 + 2] = s2 * INVS8;
    }
#pragma unroll
    for (int v = 0; v < 8; ++v) {
        float s0 = 0.f, s1 = 0.f, s2 = 0.f;
#pragma unroll
        for (int w = 0; w < 8; ++w) {
            float wd = WD1[w * 8 + v];
            s0 = fmaf(q1[w * 3 + 0], wd, s0);
            s1 = fmaf(q1[w * 3 + 1], wd, s1);
            s2 = fmaf(q1[w * 3 + 2], wd, s2);
        }
        const float sc = INVS320 * INV_SQRT3;
        pn[16 + v * 3 + 0] = sanitize(s0 * sc);
        pn[16 + v * 3 + 1] = sanitize(s1 * sc);
        pn[16 + v * 3 + 2] = sanitize(s2 * sc);
    }
}

// ---------------- fused radial @ fctp pass ----------------
__device__ __forceinline__ void fctp_pass(
    const float* __restrict__ W2, const float* h_s, int tid, float sh0,
    const float (&xs0)[16], const float (&xs1)[24], const float (&dot11)[8],
    float (&o0)[16], float (&o1)[24], float (&t2a)[8])
{
#pragma unroll 1
    for (int c = 0; c < 16; ++c) {
        float hc = h_s[c * 256 + tid];
        float hs = hc * sh0;
        const float* row = W2 + c * 576;
#pragma unroll
        for (int u = 0; u < 16; ++u) {
            float au = hs * xs0[u];
            const float* r = row + u * 16;
#pragma unroll
            for (int wo = 0; wo < 16; ++wo) o0[wo] = fmaf(r[wo], au, o0[wo]);
        }
#pragma unroll
        for (int u = 0; u < 16; ++u) {
            float bu = hc * xs0[u];
            const float* r = row + 256 + u * 8;
#pragma unroll
            for (int wo = 0; wo < 8; ++wo) t2a[wo] = fmaf(r[wo], bu, t2a[wo]);
        }
#pragma unroll
        for (int u = 0; u < 8; ++u) {
            float c0 = hs * xs1[u * 3 + 0];
            float c1 = hs * xs1[u * 3 + 1];
            float c2 = hs * xs1[u * 3 + 2];
            const float* r = row + 384 + u * 8;
#pragma unroll
            for (int wo = 0; wo < 8; ++wo) {
                float rv = r[wo];
                o1[wo * 3 + 0] = fmaf(rv, c0, o1[wo * 3 + 0]);
                o1[wo * 3 + 1] = fmaf(rv, c1, o1[wo * 3 + 1]);
                o1[wo * 3 + 2] = fmaf(rv, c2, o1[wo * 3 + 2]);
            }
        }
#pragma unroll
        for (int u = 0; u < 8; ++u) {
            float du = hc * dot11[u];
            const float* r = row + 448 + u * 16;
#pragma unroll
            for (int wo = 0; wo < 16; ++wo) o0[wo] = fmaf(r[wo], du, o0[wo]);
        }
    }
}

// ---------------- per-edge main kernel ----------------
__global__ __launch_bounds__(256) void edge_kernel(
    const int* __restrict__ ei, float* __restrict__ ws)
{
    __shared__ float hk_s[16 * 256];
    __shared__ float hv_s[16 * 256];
    const int tid = threadIdx.x;
    const int e = blockIdx.x * 256 + tid;
    if (e >= E_CNT) return;

    const float d = ws[OFF_AMFF + e];
    const float dsv = d * INV_STEP;
    float emb[16];
#pragma unroll
    for (int b = 0; b < 16; ++b) {
        float t1 = dsv - (float)b;
        float t2 = (float)(b + 2) - dsv;
        float v = 0.f;
        if (t1 > 0.f && t2 > 0.f) v = EMB_C * expf(-1.f / t1 - 1.f / t2);
        emb[b] = v;
    }
    float ct = 10.f * (1.f - d * 0.125f);
    float cutoff = (ct > 0.f) ? expf(-1.f / ct) : 0.f;

    const float* WK1 = ws + OFF_WK1F;
    const float* WV1 = ws + OFF_WV1F;

#pragma unroll 1
    for (int j = 0; j < 16; ++j) {
        float sk = 0.f, sv = 0.f;
#pragma unroll
        for (int b = 0; b < 16; ++b) {
            float eb = emb[b];
            sk = fmaf(eb, WK1[b * 16 + j], sk);
            sv = fmaf(eb, WV1[b * 16 + j], sv);
        }
        sk *= 0.25f; sv *= 0.25f;
        hk_s[j * 256 + tid] = sk / (1.f + expf(-sk));
        hv_s[j * 256 + tid] = sv / (1.f + expf(-sv));
    }

    const int src = ei[e];
    const int dst = ei[E_CNT + e];

    float xs0[16], xs1[24];
    {
        const float4* xr = (const float4*)(ws + OFF_XF + src * 40);
#pragma unroll
        for (int k = 0; k < 4; ++k) {
            float4 f = xr[k];
            xs0[4 * k] = f.x; xs0[4 * k + 1] = f.y; xs0[4 * k + 2] = f.z; xs0[4 * k + 3] = f.w;
        }
#pragma unroll
        for (int k = 0; k < 6; ++k) {
            float4 f = xr[4 + k];
            xs1[4 * k] = f.x; xs1[4 * k + 1] = f.y; xs1[4 * k + 2] = f.z; xs1[4 * k + 3] = f.w;
        }
    }
    const float4 eav = ((const float4*)(ws + OFF_EAF))[e];
    const float sh0 = eav.x, sh1x = eav.y, sh1y = eav.z, sh1z = eav.w;

    float dot11[8];
#pragma unroll
    for (int u = 0; u < 8; ++u)
        dot11[u] = (xs1[u * 3] * sh1x + xs1[u * 3 + 1] * sh1y + xs1[u * 3 + 2] * sh1z) * INV_SQRT3;

    float o0[16], o1[24], t2a[8];

    // ================= K pass =================
#pragma unroll
    for (int i = 0; i < 16; ++i) o0[i] = 0.f;
#pragma unroll
    for (int i = 0; i < 24; ++i) o1[i] = 0.f;
#pragma unroll
    for (int i = 0; i < 8; ++i) t2a[i] = 0.f;
    fctp_pass(ws + OFF_WK2F, hk_s, tid, sh0, xs0, xs1, dot11, o0, o1, t2a);
#pragma unroll
    for (int wo = 0; wo < 8; ++wo) {
        o1[wo * 3 + 0] = fmaf(t2a[wo], sh1x, o1[wo * 3 + 0]);
        o1[wo * 3 + 1] = fmaf(t2a[wo], sh1y, o1[wo * 3 + 1]);
        o1[wo * 3 + 2] = fmaf(t2a[wo], sh1z, o1[wo * 3 + 2]);
    }
    const float* pd = ws + OFF_P + dst * 40;
    float sc = 0.f;
#pragma unroll
    for (int j = 0; j < 16; ++j) sc = fmaf(o0[j], pd[j], sc);
#pragma unroll
    for (int j = 0; j < 24; ++j) sc = fmaf(o1[j], pd[16 + j], sc);
    sc = fminf(fmaxf(sc * KSCALE, -60.f), 60.f);
    float ev = cutoff * expf(sc);
    ws[OFF_EXPV + e] = fmaxf(ev, 0.f);

    // ================= V pass =================
#pragma unroll
    for (int i = 0; i < 16; ++i) o0[i] = 0.f;
#pragma unroll
    for (int i = 0; i < 24; ++i) o1[i] = 0.f;
#pragma unroll
    for (int i = 0; i < 8; ++i) t2a[i] = 0.f;
    fctp_pass(ws + OFF_WV2F, hv_s, tid, sh0, xs0, xs1, dot11, o0, o1, t2a);
#pragma unroll
    for (int wo = 0; wo < 8; ++wo) {
        o1[wo * 3 + 0] = fmaf(t2a[wo], sh1x, o1[wo * 3 + 0]);
        o1[wo * 3 + 1] = fmaf(t2a[wo], sh1y, o1[wo * 3 + 1]);
        o1[wo * 3 + 2] = fmaf(t2a[wo], sh1z, o1[wo * 3 + 2]);
    }
    float* vr = ws + OFF_VBUF + (size_t)e * 40;
#pragma unroll
    for (int j = 0; j < 16; ++j) vr[j] = sanitize(o0[j] * KSCALE);
#pragma unroll
    for (int j = 0; j < 24; ++j) vr[16 + j] = sanitize(o1[j] * KSCALE);
}

// ---------------- gather: one thread per (node, feature) ----------------
__global__ __launch_bounds__(256) void gather_kernel(
    const float* __restrict__ ws, void* __restrict__ out)
{
    const int i = blockIdx.x * 256 + threadIdx.x;
    if (i >= N_CNT * 40) return;
    const int n = i / 40;
    const int f = i - n * 40;
    const int* start = (const int*)(ws + OFF_START);
    const int* elist = (const int*)(ws + OFF_ELIST);
    const float* expv = ws + OFF_EXPV;
    const float* Vbuf = ws + OFF_VBUF;
    const int s = start[n], t = start[n + 1];

    float z = 0.f;
    for (int j = s; j < t; ++j) z += expv[elist[j]];
    z = (z > 0.f) ? z : 1.f;
    const float rz = 1.f / z;

    float acc = 0.f;
    for (int j = s; j < t; ++j) {
        const int e = elist[j];
        const float we = sqrtf(fmaxf(expv[e] * rz, 0.f));
        acc = fmaf(we, Vbuf[(size_t)e * 40 + f], acc);
    }
    acc = sanitize(acc);
    const int f32 = *(const int*)ws;
    if (f32) ((float*)out)[i] = acc;
    else     ((__hip_bfloat16*)out)[i] = __float2bfloat16(acc);
}

extern "C" void kernel_launch(void* const* d_in, const int* in_sizes, int n_in,
                              void* d_out, int out_size, void* d_ws, size_t ws_size,
                              hipStream_t stream)
{
    (void)in_sizes; (void)n_in; (void)out_size; (void)ws_size;
    const void* x   = d_in[0];
    const int*  ei  = (const int*)d_in[1];
    const void* ea  = d_in[2];
    const void* amf = d_in[5];
    const void* Wq0 = d_in[6];
    const void* Wq1 = d_in[7];
    const void* Wk1 = d_in[8];
    const void* Wk2 = d_in[9];
    const void* Wv1 = d_in[10];
    const void* Wv2 = d_in[11];
    const void* Wd0 = d_in[12];
    const void* Wd1 = d_in[13];

    float* ws = (float*)d_ws;

    detect_kernel<<<1, 64, 0, stream>>>((const unsigned short*)x, (int*)ws);
    hipMemsetAsync(ws + OFF_DEG, 0, 10000 * sizeof(int), stream);
    ingest_kernel<<<2500, 256, 0, stream>>>(x, ea, amf, Wq0, Wq1, Wk1, Wk2, Wv1, Wv2, Wd0, Wd1, ws);
    count_kernel<<<625, 256, 0, stream>>>(ei, ws);
    scan_kernel<<<1, 256, 0, stream>>>(ws);
    fill_kernel<<<625, 256, 0, stream>>>(ei, ws);
    node_kernel<<<(N_CNT + 255) / 256, 256, 0, stream>>>(ws);
    edge_kernel<<<E_CNT / 256, 256, 0, stream>>>(ei, ws);
    gather_kernel<<<(N_CNT * 40 + 255) / 256, 256, 0, stream>>>(ws, d_out);
}

// Round 5
// 381.803 us; speedup vs baseline: 1.9662x; 1.2527x over previous
//
#include <hip/hip_runtime.h>
#include <hip/hip_bf16.h>

#define E_CNT 160000
#define N_CNT 10000

#define INV_STEP   2.125f          /* 17/8 */
#define EMB_C      33.734292f      /* 1.14136 * e^2 * sqrt(16) */
#define INVS320    0.05590170f     /* 1/sqrt(320) */
#define INVS8      0.35355339f     /* 1/sqrt(8)   */
#define INV_SQRT3  0.57735027f
#define KSCALE     0.051031036f    /* 0.25 (w/sqrt16) * 1/sqrt(24) (fctp norm) */

/* ---- workspace layout (float-sized offsets) ---- */
#define OFF_FLAG   0          /* 16 floats reserved (int flag at [0]) */
#define OFF_XF     16         /* 400000 */
#define OFF_EAF    400016     /* 640000 */
#define OFF_AMFF   1040016    /* 160000 */
#define OFF_WQ0F   1200016    /* 256 */
#define OFF_WQ1F   1200272    /* 64  */
#define OFF_WD0F   1200336    /* 256 */
#define OFF_WD1F   1200592    /* 64  */
#define OFF_WK1F   1200656    /* 256 */
#define OFF_WV1F   1200912    /* 256 */
#define OFF_WK2F   1201168    /* 9216 */
#define OFF_WV2F   1210384    /* 9216 */
#define OFF_P      1219600    /* 400000 */
#define OFF_EXPV   1619600    /* 160000 */
#define OFF_VBUF   1779600    /* 6400000 */
#define OFF_DEG    8179600    /* 10000 ints  (dst) */
#define OFF_START  8189600    /* 10001 ints */
#define OFF_CURS   8199616    /* 10000 ints */
#define OFF_ELIST  8209616    /* 160000 ints */
#define OFF_DEG2   8369616    /* 10000 ints  (src) */
#define OFF_START2 8379616    /* 10001 ints */
#define OFF_CURS2  8389632    /* 10000 ints */
#define OFF_ELIST2 8399632    /* 160000 ints */
#define OFF_G      8559632    /* 30,720,000 bf16 = 15,360,000 float slots */
/* total 23,919,632 floats = 95.7 MB (verified mapped: R4 G writes did not fault) */

static __device__ __forceinline__ float bf2f(__hip_bfloat16 b) { return __bfloat162float(b); }
static __device__ __forceinline__ float sanitize(float v) {
    return fminf(fmaxf(v, -1e30f), 1e30f);
}
static __device__ __forceinline__ unsigned short f2bf(float f) {
    unsigned x = __float_as_uint(f);
    unsigned r = (x + 0x7fffu + ((x >> 16) & 1u)) >> 16;   /* RN-even */
    return (unsigned short)r;
}
static __device__ __forceinline__ float bflo(unsigned u) { return __uint_as_float(u << 16); }
static __device__ __forceinline__ float bfhi(unsigned u) { return __uint_as_float(u & 0xffff0000u); }

// ---------------- dtype detect ----------------
__global__ void detect_kernel(const unsigned short* __restrict__ xb, int* __restrict__ flag)
{
    if (threadIdx.x == 0 && blockIdx.x == 0) {
        int cnt = 0;
        for (int k = 0; k < 256; k += 2) {
            unsigned e = (unsigned)((xb[k] >> 7) & 0xFF);
            if (e >= 141) ++cnt;
        }
        *flag = (cnt >= 8) ? 1 : 0;   /* 1 = inputs are fp32 */
    }
}

// ---------------- ingest ----------------
__global__ __launch_bounds__(256) void ingest_kernel(
    const void* __restrict__ x,   const void* __restrict__ ea,  const void* __restrict__ amf,
    const void* __restrict__ Wq0, const void* __restrict__ Wq1,
    const void* __restrict__ Wk1, const void* __restrict__ Wk2,
    const void* __restrict__ Wv1, const void* __restrict__ Wv2,
    const void* __restrict__ Wd0, const void* __restrict__ Wd1,
    float* __restrict__ ws)
{
    const int i = blockIdx.x * 256 + threadIdx.x;
    const int f32 = *(const int*)ws;
#define CV(p, idx) (f32 ? ((const float*)(p))[idx] : bf2f(((const __hip_bfloat16*)(p))[idx]))
    if (i < 400000) ws[OFF_XF + i]   = CV(x, i);
    if (i < 640000) ws[OFF_EAF + i]  = CV(ea, i);
    if (i < 160000) ws[OFF_AMFF + i] = CV(amf, i);
    if (i < 9216) { ws[OFF_WK2F + i] = CV(Wk2, i); ws[OFF_WV2F + i] = CV(Wv2, i); }
    if (i < 256) {
        ws[OFF_WQ0F + i] = CV(Wq0, i); ws[OFF_WD0F + i] = CV(Wd0, i);
        ws[OFF_WK1F + i] = CV(Wk1, i); ws[OFF_WV1F + i] = CV(Wv1, i);
    }
    if (i < 64) { ws[OFF_WQ1F + i] = CV(Wq1, i); ws[OFF_WD1F + i] = CV(Wd1, i); }
#undef CV
}

// ---------------- CSR build (parameterized: row=0 src, row=1 dst) ----------------
__global__ __launch_bounds__(256) void count_kernel(
    const int* __restrict__ ei, float* __restrict__ ws, int row, int degOff)
{
    const int e = blockIdx.x * 256 + threadIdx.x;
    if (e >= E_CNT) return;
    atomicAdd((int*)(ws + degOff) + ei[row * E_CNT + e], 1);
}

__global__ __launch_bounds__(256) void scan_kernel(
    float* __restrict__ ws, int degOff, int startOff, int cursOff)
{
    __shared__ int ssum[256];
    const int t = threadIdx.x;
    int* deg   = (int*)(ws + degOff);
    int* start = (int*)(ws + startOff);
    int* curs  = (int*)(ws + cursOff);
    const int base = t * 40;
    int s = 0;
    for (int k = 0; k < 40; ++k) {
        int idx = base + k;
        if (idx < N_CNT) s += deg[idx];
    }
    ssum[t] = s;
    __syncthreads();
    for (int off = 1; off < 256; off <<= 1) {
        int v = (t >= off) ? ssum[t - off] : 0;
        __syncthreads();
        ssum[t] += v;
        __syncthreads();
    }
    int run = ssum[t] - s;
    for (int k = 0; k < 40; ++k) {
        int idx = base + k;
        if (idx < N_CNT) {
            start[idx] = run;
            curs[idx]  = run;
            run += deg[idx];
        }
    }
    if (t == 255) start[N_CNT] = E_CNT;
}

__global__ __launch_bounds__(256) void fill_kernel(
    const int* __restrict__ ei, float* __restrict__ ws, int row, int cursOff, int elistOff)
{
    const int e = blockIdx.x * 256 + threadIdx.x;
    if (e >= E_CNT) return;
    int pos = atomicAdd((int*)(ws + cursOff) + ei[row * E_CNT + e], 1);
    ((int*)(ws + elistOff))[pos] = e;
}

// ---------------- per-node P (folded Q@Wd) ----------------
__global__ __launch_bounds__(256) void node_kernel(float* __restrict__ ws)
{
    const int n = blockIdx.x * 256 + threadIdx.x;
    if (n >= N_CNT) return;
    const float* WQ0 = ws + OFF_WQ0F;
    const float* WQ1 = ws + OFF_WQ1F;
    const float* WD0 = ws + OFF_WD0F;
    const float* WD1 = ws + OFF_WD1F;
    float xs[40];
    const float4* xr = (const float4*)(ws + OFF_XF + n * 40);
#pragma unroll
    for (int k = 0; k < 10; ++k) {
        float4 f = xr[k];
        xs[4 * k + 0] = f.x; xs[4 * k + 1] = f.y; xs[4 * k + 2] = f.z; xs[4 * k + 3] = f.w;
    }
    float q0[16];
#pragma unroll
    for (int w = 0; w < 16; ++w) {
        float s = 0.f;
#pragma unroll
        for (int u = 0; u < 16; ++u) s = fmaf(xs[u], WQ0[u * 16 + w], s);
        q0[w] = s * 0.25f;
    }
    float* pn = ws + OFF_P + n * 40;
#pragma unroll
    for (int v = 0; v < 16; ++v) {
        float s = 0.f;
#pragma unroll
        for (int w = 0; w < 16; ++w) s = fmaf(q0[w], WD0[w * 16 + v], s);
        pn[v] = sanitize(s * INVS320);
    }
    float q1[24];
#pragma unroll
    for (int w = 0; w < 8; ++w) {
        float s0 = 0.f, s1 = 0.f, s2 = 0.f;
#pragma unroll
        for (int u = 0; u < 8; ++u) {
            float wq = WQ1[u * 8 + w];
            s0 = fmaf(xs[16 + u * 3 + 0], wq, s0);
            s1 = fmaf(xs[16 + u * 3 + 1], wq, s1);
            s2 = fmaf(xs[16 + u * 3 + 2], wq, s2);
        }
        q1[w * 3 + 0] = s0 * INVS8;
        q1[w * 3 + 1] = s1 * INVS8;
        q1[w * 3 + 2] = s2 * INVS8;
    }
#pragma unroll
    for (int v = 0; v < 8; ++v) {
        float s0 = 0.f, s1 = 0.f, s2 = 0.f;
#pragma unroll
        for (int w = 0; w < 8; ++w) {
            float wd = WD1[w * 8 + v];
            s0 = fmaf(q1[w * 3 + 0], wd, s0);
            s1 = fmaf(q1[w * 3 + 1], wd, s1);
            s2 = fmaf(q1[w * 3 + 2], wd, s2);
        }
        const float sc = INVS320 * INV_SQRT3;
        pn[16 + v * 3 + 0] = sanitize(s0 * sc);
        pn[16 + v * 3 + 1] = sanitize(s1 * sc);
        pn[16 + v * 3 + 2] = sanitize(s2 * sc);
    }
}

// ---------------- per-node G tables: thread = (pass, c, node) ----------------
// Row layout per (n,p,c): 96 bf16 values = 48 u32 = 12 uint4.
// [0..15] G1[w], [16..23] G2[w], [24+w*3+i] G3[w][i] (w<8),
// [48+w*3+i] G4[w][i] (w<16, 1/sqrt3 folded)
__global__ __launch_bounds__(256) void nodeg_kernel(float* __restrict__ ws)
{
    const int t = blockIdx.x * 256 + threadIdx.x;      /* 1250 blocks * 256 = 320000 */
    if (t >= 320000) return;
    const int p   = t / 160000;
    const int rem = t - p * 160000;
    const int c   = rem / 10000;
    const int n   = rem - c * 10000;

    const float* W2 = ws + (p ? OFF_WV2F : OFF_WK2F) + c * 576;
    const float* xv = ws + OFF_XF + n * 40;
    float x0[16], x1[24];
#pragma unroll
    for (int u = 0; u < 16; ++u) x0[u] = xv[u];
#pragma unroll
    for (int u = 0; u < 24; ++u) x1[u] = xv[16 + u];

    float out[96];
#pragma unroll
    for (int w = 0; w < 16; ++w) {
        float s = 0.f;
#pragma unroll
        for (int u = 0; u < 16; ++u) s = fmaf(W2[u * 16 + w], x0[u], s);
        out[w] = s;
    }
#pragma unroll
    for (int w = 0; w < 8; ++w) {
        float s = 0.f;
#pragma unroll
        for (int u = 0; u < 16; ++u) s = fmaf(W2[256 + u * 8 + w], x0[u], s);
        out[16 + w] = s;
    }
#pragma unroll
    for (int w = 0; w < 8; ++w) {
        float s0 = 0.f, s1 = 0.f, s2 = 0.f;
#pragma unroll
        for (int u = 0; u < 8; ++u) {
            float wv = W2[384 + u * 8 + w];
            s0 = fmaf(wv, x1[u * 3 + 0], s0);
            s1 = fmaf(wv, x1[u * 3 + 1], s1);
            s2 = fmaf(wv, x1[u * 3 + 2], s2);
        }
        out[24 + w * 3 + 0] = s0;
        out[24 + w * 3 + 1] = s1;
        out[24 + w * 3 + 2] = s2;
    }
#pragma unroll
    for (int w = 0; w < 16; ++w) {
        float s0 = 0.f, s1 = 0.f, s2 = 0.f;
#pragma unroll
        for (int u = 0; u < 8; ++u) {
            float wv = W2[448 + u * 16 + w];
            s0 = fmaf(wv, x1[u * 3 + 0], s0);
            s1 = fmaf(wv, x1[u * 3 + 1], s1);
            s2 = fmaf(wv, x1[u * 3 + 2], s2);
        }
        out[48 + w * 3 + 0] = s0 * INV_SQRT3;
        out[48 + w * 3 + 1] = s1 * INV_SQRT3;
        out[48 + w * 3 + 2] = s2 * INV_SQRT3;
    }

    uint4 ov[12];                                   /* 96 bf16 = 48 u32 = 12 uint4 */
    unsigned* ou = (unsigned*)ov;
#pragma unroll
    for (int k = 0; k < 48; ++k)
        ou[k] = (unsigned)f2bf(out[2 * k]) | ((unsigned)f2bf(out[2 * k + 1]) << 16);
    uint4* dp = (uint4*)((unsigned short*)(ws + OFF_G) + ((size_t)n * 2 + p) * 1536 + c * 96);
#pragma unroll
    for (int q = 0; q < 12; ++q) dp[q] = ov[q];
}

// ---------------- per-edge main kernel: 2 threads/edge (K-pass, V-pass) ----------------
__global__ __launch_bounds__(256) void edge_kernel(
    const int* __restrict__ ei, float* __restrict__ ws)
{
    __shared__ float h_s[16 * 256];     /* per-thread h, dynamically indexed by c */
    const int tid  = threadIdx.x;
    const int pass = tid >> 7;          /* waves 0-1: K, waves 2-3: V */
    const int lane = tid & 127;
    const int sidx = blockIdx.x * 128 + lane;   /* src-sorted edge index */
    const int e    = ((const int*)(ws + OFF_ELIST2))[sidx];
    const int src  = ei[e];
    const int dst  = ei[E_CNT + e];

    const float d   = ws[OFF_AMFF + e];
    const float dsv = d * INV_STEP;
    float emb[16];
#pragma unroll
    for (int b = 0; b < 16; ++b) {
        float t1 = dsv - (float)b;
        float t2 = (float)(b + 2) - dsv;
        float v = 0.f;
        if (t1 > 0.f && t2 > 0.f) v = EMB_C * expf(-1.f / t1 - 1.f / t2);
        emb[b] = v;
    }

    const float* W1 = ws + (pass ? OFF_WV1F : OFF_WK1F);
#pragma unroll 1
    for (int j = 0; j < 16; ++j) {
        float s = 0.f;
#pragma unroll
        for (int b = 0; b < 16; ++b) s = fmaf(emb[b], W1[b * 16 + j], s);
        s *= 0.25f;
        h_s[j * 256 + tid] = s / (1.f + expf(-s));
    }

    const float4 eav = ((const float4*)(ws + OFF_EAF))[e];
    const float sh0 = eav.x, s1x = eav.y, s1y = eav.z, s1z = eav.w;

    float o0[16], o1[24], t2a[8];
#pragma unroll
    for (int i = 0; i < 16; ++i) o0[i] = 0.f;
#pragma unroll
    for (int i = 0; i < 24; ++i) o1[i] = 0.f;
#pragma unroll
    for (int i = 0; i < 8; ++i) t2a[i] = 0.f;

    const uint4* Gp = (const uint4*)((const unsigned short*)(ws + OFF_G)
                                     + ((size_t)src * 2 + pass) * 1536);
#pragma unroll 1
    for (int c = 0; c < 16; ++c) {
        const float hc = h_s[c * 256 + tid];
        const float hs = hc * sh0;
        unsigned ub[48];                             /* 96 bf16 = 48 u32 */
        {
            const uint4* rp = Gp + c * 12;           /* 12 uint4 per (c) row */
#pragma unroll
            for (int q = 0; q < 12; ++q) {
                uint4 v = rp[q];
                ub[4 * q + 0] = v.x; ub[4 * q + 1] = v.y;
                ub[4 * q + 2] = v.z; ub[4 * q + 3] = v.w;
            }
        }
#define GVAL(k) (((k) & 1) ? bfhi(ub[(k) >> 1]) : bflo(ub[(k) >> 1]))
#pragma unroll
        for (int w = 0; w < 16; ++w) o0[w] = fmaf(hs, GVAL(w), o0[w]);
#pragma unroll
        for (int w = 0; w < 8; ++w) t2a[w] = fmaf(hc, GVAL(16 + w), t2a[w]);
#pragma unroll
        for (int w = 0; w < 8; ++w) {
            o1[w * 3 + 0] = fmaf(hs, GVAL(24 + w * 3 + 0), o1[w * 3 + 0]);
            o1[w * 3 + 1] = fmaf(hs, GVAL(24 + w * 3 + 1), o1[w * 3 + 1]);
            o1[w * 3 + 2] = fmaf(hs, GVAL(24 + w * 3 + 2), o1[w * 3 + 2]);
        }
#pragma unroll
        for (int w = 0; w < 16; ++w) {
            float g = GVAL(48 + w * 3 + 0) * s1x;
            g = fmaf(GVAL(48 + w * 3 + 1), s1y, g);
            g = fmaf(GVAL(48 + w * 3 + 2), s1z, g);
            o0[w] = fmaf(hc, g, o0[w]);
        }
#undef GVAL
    }

#pragma unroll
    for (int w = 0; w < 8; ++w) {
        o1[w * 3 + 0] = fmaf(t2a[w], s1x, o1[w * 3 + 0]);
        o1[w * 3 + 1] = fmaf(t2a[w], s1y, o1[w * 3 + 1]);
        o1[w * 3 + 2] = fmaf(t2a[w], s1z, o1[w * 3 + 2]);
    }

    if (pass == 0) {
        const float* pd = ws + OFF_P + dst * 40;
        float sc = 0.f;
#pragma unroll
        for (int j = 0; j < 16; ++j) sc = fmaf(o0[j], pd[j], sc);
#pragma unroll
        for (int j = 0; j < 24; ++j) sc = fmaf(o1[j], pd[16 + j], sc);
        sc = fminf(fmaxf(sc * KSCALE, -60.f), 60.f);
        float ct = 10.f * (1.f - d * 0.125f);
        float cutoff = (ct > 0.f) ? expf(-1.f / ct) : 0.f;
        float ev = cutoff * expf(sc);
        ws[OFF_EXPV + e] = fmaxf(ev, 0.f);
    } else {
        float* vr = ws + OFF_VBUF + (size_t)e * 40;
#pragma unroll
        for (int j = 0; j < 16; ++j) vr[j] = sanitize(o0[j] * KSCALE);
#pragma unroll
        for (int j = 0; j < 24; ++j) vr[16 + j] = sanitize(o1[j] * KSCALE);
    }
}

// ---------------- gather: one thread per (node, feature) ----------------
__global__ __launch_bounds__(256) void gather_kernel(
    const float* __restrict__ ws, void* __restrict__ out)
{
    const int i = blockIdx.x * 256 + threadIdx.x;
    if (i >= N_CNT * 40) return;
    const int n = i / 40;
    const int f = i - n * 40;
    const int* start = (const int*)(ws + OFF_START);
    const int* elist = (const int*)(ws + OFF_ELIST);
    const float* expv = ws + OFF_EXPV;
    const float* Vbuf = ws + OFF_VBUF;
    const int s = start[n], t = start[n + 1];

    float z = 0.f;
    for (int j = s; j < t; ++j) z += expv[elist[j]];
    z = (z > 0.f) ? z : 1.f;
    const float rz = 1.f / z;

    float acc = 0.f;
    for (int j = s; j < t; ++j) {
        const int e = elist[j];
        const float we = sqrtf(fmaxf(expv[e] * rz, 0.f));
        acc = fmaf(we, Vbuf[(size_t)e * 40 + f], acc);
    }
    acc = sanitize(acc);
    const int f32 = *(const int*)ws;
    if (f32) ((float*)out)[i] = acc;
    else     ((__hip_bfloat16*)out)[i] = __float2bfloat16(acc);
}

extern "C" void kernel_launch(void* const* d_in, const int* in_sizes, int n_in,
                              void* d_out, int out_size, void* d_ws, size_t ws_size,
                              hipStream_t stream)
{
    (void)in_sizes; (void)n_in; (void)out_size; (void)ws_size;
    const void* x   = d_in[0];
    const int*  ei  = (const int*)d_in[1];
    const void* ea  = d_in[2];
    const void* amf = d_in[5];
    const void* Wq0 = d_in[6];
    const void* Wq1 = d_in[7];
    const void* Wk1 = d_in[8];
    const void* Wk2 = d_in[9];
    const void* Wv1 = d_in[10];
    const void* Wv2 = d_in[11];
    const void* Wd0 = d_in[12];
    const void* Wd1 = d_in[13];

    float* ws = (float*)d_ws;

    detect_kernel<<<1, 64, 0, stream>>>((const unsigned short*)x, (int*)ws);
    hipMemsetAsync(ws + OFF_DEG,  0, 10000 * sizeof(int), stream);
    hipMemsetAsync(ws + OFF_DEG2, 0, 10000 * sizeof(int), stream);
    ingest_kernel<<<2500, 256, 0, stream>>>(x, ea, amf, Wq0, Wq1, Wk1, Wk2, Wv1, Wv2, Wd0, Wd1, ws);
    /* dst-CSR (for gather) */
    count_kernel<<<625, 256, 0, stream>>>(ei, ws, 1, OFF_DEG);
    scan_kernel<<<1, 256, 0, stream>>>(ws, OFF_DEG, OFF_START, OFF_CURS);
    fill_kernel<<<625, 256, 0, stream>>>(ei, ws, 1, OFF_CURS, OFF_ELIST);
    /* src-CSR (for edge ordering / G locality) */
    count_kernel<<<625, 256, 0, stream>>>(ei, ws, 0, OFF_DEG2);
    scan_kernel<<<1, 256, 0, stream>>>(ws, OFF_DEG2, OFF_START2, OFF_CURS2);
    fill_kernel<<<625, 256, 0, stream>>>(ei, ws, 0, OFF_CURS2, OFF_ELIST2);
    node_kernel<<<(N_CNT + 255) / 256, 256, 0, stream>>>(ws);
    nodeg_kernel<<<1250, 256, 0, stream>>>(ws);
    edge_kernel<<<1250, 256, 0, stream>>>(ei, ws);
    gather_kernel<<<(N_CNT * 40 + 255) / 256, 256, 0, stream>>>(ws, d_out);
}